// Round 1
// baseline (366.424 us; speedup 1.0000x reference)
//
#include <hip/hip_runtime.h>
#include <stdint.h>

#define B_DIM 4
#define T_DIM 2048
#define C_DIM 1024
#define H_DIM 16
#define D_DIM 64
#define M_DIM (B_DIM * T_DIM)   // 8192

typedef float f32x4 __attribute__((ext_vector_type(4)));
typedef short bf16x8 __attribute__((ext_vector_type(8)));
typedef unsigned short u16;
typedef u16 u16x8 __attribute__((ext_vector_type(8)));

static __device__ __forceinline__ u16 f2b(float f) {
  union { float f; uint32_t u; } v; v.f = f;
  uint32_t r = v.u + 0x7fffu + ((v.u >> 16) & 1u);   // RNE
  return (u16)(r >> 16);
}

static __device__ __forceinline__ void gl_lds16(const u16* g, u16* l) {
  __builtin_amdgcn_global_load_lds(
      (const __attribute__((address_space(1))) void*)g,
      (__attribute__((address_space(3))) void*)l, 16, 0, 0);
}

// ---------------- f32 -> bf16 convert ----------------
__global__ void k_cvt(const float* __restrict__ src, u16* __restrict__ dst, int n4) {
  int i = blockIdx.x * blockDim.x + threadIdx.x;
  if (i < n4) {
    float4 v = ((const float4*)src)[i];
    ushort4 o;
    o.x = f2b(v.x); o.y = f2b(v.y); o.z = f2b(v.z); o.w = f2b(v.w);
    ((ushort4*)dst)[i] = o;
  }
}

// ---------------- GEMM: C = A @ Bw^T + bias ----------------
// A [M][K] bf16 row-major, Bw [N][K] bf16 row-major (torch linear weight).
// MODE 0: out float [M][N]
// MODE 1: out bf16 [B,H,T,D] split-head layout, val *= scale   (Q)
// MODE 2: out bf16 [B,H,T,D]                                    (K, V)
template <int MODE>
__global__ __launch_bounds__(256) void k_gemm(
    const u16* __restrict__ A, const u16* __restrict__ Bw,
    const float* __restrict__ bias, void* __restrict__ Cout,
    int M, int N, int K, float scale) {
  __shared__ u16 As[128 * 32];
  __shared__ u16 Bs[128 * 32];
  const int tid = threadIdx.x;
  const int l = tid & 63;
  const int w = tid >> 6;
  const int wr = w >> 1, wc = w & 1;
  const int brow = blockIdx.y * 128, bcol = blockIdx.x * 128;
  const int lrow = l & 15, lk = l >> 4;

  f32x4 acc[4][4];
  for (int m = 0; m < 4; ++m)
    for (int n = 0; n < 4; ++n)
      acc[m][n] = (f32x4){0.f, 0.f, 0.f, 0.f};

  for (int kt = 0; kt < K; kt += 32) {
    __syncthreads();
    {
      int slot = tid;
      int r0 = slot >> 2, b0 = slot & 3;
      gl_lds16(A + (size_t)(brow + r0) * K + kt + b0 * 8, As + slot * 8);
      gl_lds16(Bw + (size_t)(bcol + r0) * K + kt + b0 * 8, Bs + slot * 8);
      int slot2 = slot + 256;
      int r1 = slot2 >> 2, b1 = slot2 & 3;
      gl_lds16(A + (size_t)(brow + r1) * K + kt + b1 * 8, As + slot2 * 8);
      gl_lds16(Bw + (size_t)(bcol + r1) * K + kt + b1 * 8, Bs + slot2 * 8);
    }
    asm volatile("s_waitcnt vmcnt(0)" ::: "memory");
    __syncthreads();

    bf16x8 af[4], bfr[4];
#pragma unroll
    for (int m = 0; m < 4; ++m)
      af[m] = *(const bf16x8*)(As + (wr * 64 + m * 16 + lrow) * 32 + lk * 8);
#pragma unroll
    for (int n = 0; n < 4; ++n)
      bfr[n] = *(const bf16x8*)(Bs + (wc * 64 + n * 16 + lrow) * 32 + lk * 8);
#pragma unroll
    for (int m = 0; m < 4; ++m) {
#pragma unroll
      for (int n = 0; n < 4; ++n)
        acc[m][n] = __builtin_amdgcn_mfma_f32_16x16x32_bf16(af[m], bfr[n], acc[m][n], 0, 0, 0);
    }
  }

#pragma unroll
  for (int m = 0; m < 4; ++m) {
    int rg0 = brow + wr * 64 + m * 16 + lk * 4;
#pragma unroll
    for (int n = 0; n < 4; ++n) {
      int cg = bcol + wc * 64 + n * 16 + lrow;
      float bv = bias[cg];
#pragma unroll
      for (int i = 0; i < 4; ++i) {
        int rg = rg0 + i;
        float val = acc[m][n][i] + bv;
        if (MODE == 0) {
          ((float*)Cout)[(size_t)rg * N + cg] = val;
        } else {
          if (MODE == 1) val *= scale;
          int bb = rg >> 11, tt = rg & (T_DIM - 1);
          int hh = cg >> 6, dd = cg & 63;
          ((u16*)Cout)[(((size_t)bb * H_DIM + hh) * T_DIM + tt) * D_DIM + dd] = f2b(val);
        }
      }
    }
  }
}

// ---------------- V transpose: [B,H,T,D] -> [B,H,D,T] ----------------
__global__ __launch_bounds__(256) void k_transpose(
    const u16* __restrict__ V, u16* __restrict__ Vt) {
  __shared__ u16 tile[64][65];
  const int tid = threadIdx.x;
  const int bh = blockIdx.y;
  const int t0 = blockIdx.x * 64;
  const size_t ibase = (size_t)bh * T_DIM * D_DIM + (size_t)t0 * D_DIM;
  const size_t obase = (size_t)bh * D_DIM * T_DIM + t0;

#pragma unroll
  for (int it = 0; it < 2; ++it) {
    int row = (tid >> 3) + it * 32;
    int blk = tid & 7;
    u16x8 v = *(const u16x8*)(V + ibase + (size_t)row * D_DIM + blk * 8);
#pragma unroll
    for (int j = 0; j < 8; ++j) tile[row][blk * 8 + j] = v[j];
  }
  __syncthreads();
#pragma unroll
  for (int it = 0; it < 2; ++it) {
    int d = (tid >> 3) + it * 32;
    int blk = tid & 7;
    u16x8 v;
#pragma unroll
    for (int j = 0; j < 8; ++j) v[j] = tile[blk * 8 + j][d];
    *(u16x8*)(Vt + obase + (size_t)d * T_DIM + blk * 8) = v;
  }
}

// ---------------- causal flash attention ----------------
// Q [B,H,T,D] (pre-scaled by 1/sqrt(D)), K [B,H,T,D], Vt [B,H,D,T];
// O [B,T,H*D] bf16. Block: 128 q-rows, 4 waves x 32 rows. KB=64.
__global__ __launch_bounds__(256) void k_attn(
    const u16* __restrict__ Q, const u16* __restrict__ Kg,
    const u16* __restrict__ Vt, u16* __restrict__ O) {
  __shared__ u16 Ks[64 * 64];
  __shared__ u16 Vs[64 * 64];
  __shared__ u16 Ps[4][32 * 72];   // per-wave, padded rows (72) -> conflict-free frag reads

  const int tid = threadIdx.x;
  const int l = tid & 63;
  const int w = tid >> 6;
  const int bh = blockIdx.y;
  const int q0 = blockIdx.x * 128;
  const int lrow = l & 15, lk = l >> 4;

  const size_t qkbase = (size_t)bh * T_DIM * D_DIM;
  const size_t vtbase = (size_t)bh * D_DIM * T_DIM;

  // Q fragments held in registers for the whole block
  bf16x8 qf[2][2];
#pragma unroll
  for (int m = 0; m < 2; ++m) {
#pragma unroll
    for (int kk = 0; kk < 2; ++kk)
      qf[m][kk] = *(const bf16x8*)(Q + qkbase +
          (size_t)(q0 + w * 32 + m * 16 + lrow) * D_DIM + kk * 32 + lk * 8);
  }

  f32x4 o[2][4];
  float m_run[2][4], l_run[2][4];
#pragma unroll
  for (int m = 0; m < 2; ++m) {
#pragma unroll
    for (int n = 0; n < 4; ++n) o[m][n] = (f32x4){0.f, 0.f, 0.f, 0.f};
#pragma unroll
    for (int i = 0; i < 4; ++i) { m_run[m][i] = -1e30f; l_run[m][i] = 0.f; }
  }

  const int diag = q0 >> 6;     // first k-tile needing the causal mask
  const int nkt = diag + 2;

  for (int kt = 0; kt < nkt; ++kt) {
    __syncthreads();
    {
      // stage K and Vt tiles; XOR swizzle applied on the GLOBAL source so the
      // linear global_load_lds dest ends up bank-conflict-reduced on frag reads
      int slot = tid;
      int r0 = slot >> 3, c0 = slot & 7;
      gl_lds16(Kg + qkbase + (size_t)(kt * 64 + r0) * D_DIM + ((c0 ^ (r0 & 7)) * 8), Ks + slot * 8);
      gl_lds16(Vt + vtbase + (size_t)r0 * T_DIM + kt * 64 + ((c0 ^ (r0 & 7)) * 8), Vs + slot * 8);
      int slot2 = slot + 256;
      int r1 = slot2 >> 3, c1 = slot2 & 7;
      gl_lds16(Kg + qkbase + (size_t)(kt * 64 + r1) * D_DIM + ((c1 ^ (r1 & 7)) * 8), Ks + slot2 * 8);
      gl_lds16(Vt + vtbase + (size_t)r1 * T_DIM + kt * 64 + ((c1 ^ (r1 & 7)) * 8), Vs + slot2 * 8);
    }
    asm volatile("s_waitcnt vmcnt(0)" ::: "memory");
    __syncthreads();

    // ---- S = Q @ K^T (Q pre-scaled) ----
    f32x4 s[2][4];
#pragma unroll
    for (int m = 0; m < 2; ++m)
#pragma unroll
      for (int n = 0; n < 4; ++n) s[m][n] = (f32x4){0.f, 0.f, 0.f, 0.f};

#pragma unroll
    for (int kk = 0; kk < 2; ++kk) {
      bf16x8 kf[4];
#pragma unroll
      for (int n = 0; n < 4; ++n) {
        int row = n * 16 + lrow;
        int blk = (kk * 4 + lk) ^ (row & 7);
        kf[n] = *(const bf16x8*)(Ks + row * 64 + blk * 8);
      }
#pragma unroll
      for (int m = 0; m < 2; ++m) {
#pragma unroll
        for (int n = 0; n < 4; ++n)
          s[m][n] = __builtin_amdgcn_mfma_f32_16x16x32_bf16(qf[m][kk], kf[n], s[m][n], 0, 0, 0);
      }
    }

    // ---- causal mask (diagonal tiles only) ----
    if (kt >= diag) {
#pragma unroll
      for (int m = 0; m < 2; ++m) {
#pragma unroll
        for (int i = 0; i < 4; ++i) {
          int qg = q0 + w * 32 + m * 16 + lk * 4 + i;
#pragma unroll
          for (int n = 0; n < 4; ++n) {
            int kg = kt * 64 + n * 16 + lrow;
            if (kg > qg) s[m][n][i] = -1e30f;
          }
        }
      }
    }

    // ---- online softmax (row = lk*4+i within each 16-row group) ----
#pragma unroll
    for (int m = 0; m < 2; ++m) {
      float pm[4], rs[4];
#pragma unroll
      for (int i = 0; i < 4; ++i)
        pm[i] = fmaxf(fmaxf(s[m][0][i], s[m][1][i]), fmaxf(s[m][2][i], s[m][3][i]));
#pragma unroll
      for (int off = 1; off < 16; off <<= 1) {
#pragma unroll
        for (int i = 0; i < 4; ++i)
          pm[i] = fmaxf(pm[i], __shfl_xor(pm[i], off, 64));
      }
#pragma unroll
      for (int i = 0; i < 4; ++i) {
        float mn = fmaxf(m_run[m][i], pm[i]);
        float sc = __expf(m_run[m][i] - mn);
        m_run[m][i] = mn;
        l_run[m][i] *= sc;
#pragma unroll
        for (int n = 0; n < 4; ++n) o[m][n][i] *= sc;
        pm[i] = mn;
        rs[i] = 0.f;
      }
#pragma unroll
      for (int n = 0; n < 4; ++n) {
#pragma unroll
        for (int i = 0; i < 4; ++i) {
          float p = __expf(s[m][n][i] - pm[i]);
          s[m][n][i] = p;
          rs[i] += p;
        }
      }
#pragma unroll
      for (int off = 1; off < 16; off <<= 1) {
#pragma unroll
        for (int i = 0; i < 4; ++i)
          rs[i] += __shfl_xor(rs[i], off, 64);
      }
#pragma unroll
      for (int i = 0; i < 4; ++i) l_run[m][i] += rs[i];

      // P -> per-wave LDS (C-layout rows -> A-layout frag reads)
#pragma unroll
      for (int n = 0; n < 4; ++n) {
#pragma unroll
        for (int i = 0; i < 4; ++i) {
          int prow = m * 16 + lk * 4 + i;
          Ps[w][prow * 72 + n * 16 + lrow] = f2b(s[m][n][i]);
        }
      }
    }

    // ---- O += P @ V ----
#pragma unroll
    for (int kk = 0; kk < 2; ++kk) {
      bf16x8 pf[2], vf[4];
#pragma unroll
      for (int m = 0; m < 2; ++m)
        pf[m] = *(const bf16x8*)(&Ps[w][(m * 16 + lrow) * 72 + kk * 32 + lk * 8]);
#pragma unroll
      for (int n = 0; n < 4; ++n) {
        int row = n * 16 + lrow;
        int blk = (kk * 4 + lk) ^ (row & 7);
        vf[n] = *(const bf16x8*)(Vs + row * 64 + blk * 8);
      }
#pragma unroll
      for (int m = 0; m < 2; ++m) {
#pragma unroll
        for (int n = 0; n < 4; ++n)
          o[m][n] = __builtin_amdgcn_mfma_f32_16x16x32_bf16(pf[m], vf[n], o[m][n], 0, 0, 0);
      }
    }
  }

  // ---- write O [B,T,H*D] bf16 ----
  const int bb = bh >> 4, hh = bh & 15;
#pragma unroll
  for (int m = 0; m < 2; ++m) {
#pragma unroll
    for (int i = 0; i < 4; ++i) {
      int t = q0 + w * 32 + m * 16 + lk * 4 + i;
      float inv = 1.f / l_run[m][i];
#pragma unroll
      for (int n = 0; n < 4; ++n) {
        O[((size_t)bb * T_DIM + t) * C_DIM + hh * D_DIM + n * 16 + lrow] =
            f2b(o[m][n][i] * inv);
      }
    }
  }
}

// ---------------- host launcher ----------------
extern "C" void kernel_launch(void* const* d_in, const int* in_sizes, int n_in,
                              void* d_out, int out_size, void* d_ws, size_t ws_size,
                              hipStream_t stream) {
  (void)in_sizes; (void)n_in; (void)out_size; (void)ws_size;
  const float* x  = (const float*)d_in[0];
  const float* wq = (const float*)d_in[1];
  const float* bq = (const float*)d_in[2];
  const float* wk = (const float*)d_in[3];
  const float* bk = (const float*)d_in[4];
  const float* wv = (const float*)d_in[5];
  const float* bv = (const float*)d_in[6];
  const float* wo = (const float*)d_in[7];
  const float* bo = (const float*)d_in[8];
  float* out = (float*)d_out;

  // workspace layout (bf16 elements), total ~92 MB
  u16* xb  = (u16*)d_ws;
  u16* wqb = xb + (size_t)M_DIM * C_DIM;
  u16* wkb = wqb + (size_t)C_DIM * C_DIM;
  u16* wvb = wkb + (size_t)C_DIM * C_DIM;
  u16* wob = wvb + (size_t)C_DIM * C_DIM;
  u16* Qb  = wob + (size_t)C_DIM * C_DIM;
  u16* Kb  = Qb + (size_t)M_DIM * C_DIM;
  u16* Vb  = Kb + (size_t)M_DIM * C_DIM;
  u16* Vtb = Vb + (size_t)M_DIM * C_DIM;
  u16* Ob  = Vb;  // alias: V consumed by k_transpose before k_attn writes O

  int n4x = M_DIM * C_DIM / 4;
  int n4w = C_DIM * C_DIM / 4;
  k_cvt<<<(n4x + 255) / 256, 256, 0, stream>>>(x, xb, n4x);
  k_cvt<<<(n4w + 255) / 256, 256, 0, stream>>>(wq, wqb, n4w);
  k_cvt<<<(n4w + 255) / 256, 256, 0, stream>>>(wk, wkb, n4w);
  k_cvt<<<(n4w + 255) / 256, 256, 0, stream>>>(wv, wvb, n4w);
  k_cvt<<<(n4w + 255) / 256, 256, 0, stream>>>(wo, wob, n4w);

  dim3 gg(C_DIM / 128, M_DIM / 128);
  k_gemm<1><<<gg, 256, 0, stream>>>(xb, wqb, bq, Qb, M_DIM, C_DIM, C_DIM, 0.125f);
  k_gemm<2><<<gg, 256, 0, stream>>>(xb, wkb, bk, Kb, M_DIM, C_DIM, C_DIM, 1.f);
  k_gemm<2><<<gg, 256, 0, stream>>>(xb, wvb, bv, Vb, M_DIM, C_DIM, C_DIM, 1.f);

  k_transpose<<<dim3(T_DIM / 64, B_DIM * H_DIM), 256, 0, stream>>>(Vb, Vtb);
  k_attn<<<dim3(T_DIM / 128, B_DIM * H_DIM), 256, 0, stream>>>(Qb, Kb, Vtb, Ob);
  k_gemm<0><<<gg, 256, 0, stream>>>(Ob, wob, bo, out, M_DIM, C_DIM, C_DIM, 1.f);
}

// Round 2
// 242.544 us; speedup vs baseline: 1.5107x; 1.5107x over previous
//
#include <hip/hip_runtime.h>
#include <stdint.h>

#define B_DIM 4
#define T_DIM 2048
#define C_DIM 1024
#define H_DIM 16
#define D_DIM 64
#define M_DIM (B_DIM * T_DIM)   // 8192
// 1/sqrt(D) * log2(e): QK^T lands in exp2 domain
#define QK_SCALE 0.18033688011112042f

typedef float f32x4 __attribute__((ext_vector_type(4)));
typedef short bf16x8 __attribute__((ext_vector_type(8)));
typedef unsigned short u16;
typedef u16 u16x8 __attribute__((ext_vector_type(8)));

// single-instruction RNE f32->bf16 (low 16 bits of dest)
static __device__ __forceinline__ u16 f2b(float f) {
  uint32_t r;
  asm("v_cvt_pk_bf16_f32 %0, %1, %1" : "=v"(r) : "v"(f));
  return (u16)r;
}
// pack 2 f32 -> u32 of 2 bf16 (lo=a, hi=b)
static __device__ __forceinline__ uint32_t f2b2(float a, float b) {
  uint32_t r;
  asm("v_cvt_pk_bf16_f32 %0, %1, %2" : "=v"(r) : "v"(a), "v"(b));
  return r;
}

static __device__ __forceinline__ void gl_lds16(const u16* g, u16* l) {
  __builtin_amdgcn_global_load_lds(
      (const __attribute__((address_space(1))) void*)g,
      (__attribute__((address_space(3))) void*)l, 16, 0, 0);
}

// ---------------- f32 -> bf16 converts ----------------
__global__ void k_cvt(const float* __restrict__ src, u16* __restrict__ dst, int n4) {
  int i = blockIdx.x * blockDim.x + threadIdx.x;
  if (i < n4) {
    float4 v = ((const float4*)src)[i];
    uint2 o;
    o.x = f2b2(v.x, v.y);
    o.y = f2b2(v.z, v.w);
    ((uint2*)dst)[i] = o;
  }
}

// all four weight matrices in one dispatch; each is C*C floats = 2^18 float4
__global__ void k_cvtw(const float* __restrict__ s0, const float* __restrict__ s1,
                       const float* __restrict__ s2, const float* __restrict__ s3,
                       u16* __restrict__ d0, u16* __restrict__ d1,
                       u16* __restrict__ d2, u16* __restrict__ d3) {
  int i = blockIdx.x * blockDim.x + threadIdx.x;
  int seg = i >> 18;
  int j = i & ((1 << 18) - 1);
  const float* s = seg == 0 ? s0 : seg == 1 ? s1 : seg == 2 ? s2 : s3;
  u16* d = seg == 0 ? d0 : seg == 1 ? d1 : seg == 2 ? d2 : d3;
  float4 v = ((const float4*)s)[j];
  uint2 o;
  o.x = f2b2(v.x, v.y);
  o.y = f2b2(v.z, v.w);
  ((uint2*)d)[j] = o;
}

// ---------------- fused QKV GEMM ----------------
// A [M][K] bf16, weights [C][K] bf16 (torch W, row = out col). Output split-head
// bf16 [B,H,T,D]; Q gets QK_SCALE folded in. grid = (24, M/128): x = seg*8 + colblk.
__global__ __launch_bounds__(256) void k_gemm_qkv(
    const u16* __restrict__ A,
    const u16* __restrict__ w0, const u16* __restrict__ w1, const u16* __restrict__ w2,
    const float* __restrict__ b0, const float* __restrict__ b1, const float* __restrict__ b2,
    u16* __restrict__ Qo, u16* __restrict__ Ko, u16* __restrict__ Vo) {
  __shared__ u16 As[128 * 32];
  __shared__ u16 Bs[128 * 32];
  const int tid = threadIdx.x;
  const int l = tid & 63;
  const int w = tid >> 6;
  const int wr = w >> 1, wc = w & 1;
  const int seg = blockIdx.x >> 3;
  const int brow = blockIdx.y * 128, bcol = (blockIdx.x & 7) * 128;
  const int lrow = l & 15, lk = l >> 4;
  const int K = C_DIM;

  const u16* Bw = seg == 0 ? w0 : seg == 1 ? w1 : w2;
  const float* bias = seg == 0 ? b0 : seg == 1 ? b1 : b2;
  u16* Out = seg == 0 ? Qo : seg == 1 ? Ko : Vo;
  const float scale = seg == 0 ? QK_SCALE : 1.f;

  f32x4 acc[4][4];
  for (int m = 0; m < 4; ++m)
    for (int n = 0; n < 4; ++n)
      acc[m][n] = (f32x4){0.f, 0.f, 0.f, 0.f};

  for (int kt = 0; kt < K; kt += 32) {
    __syncthreads();
    {
      int slot = tid;
      int r0 = slot >> 2, c0 = slot & 3;
      gl_lds16(A + (size_t)(brow + r0) * K + kt + c0 * 8, As + slot * 8);
      gl_lds16(Bw + (size_t)(bcol + r0) * K + kt + c0 * 8, Bs + slot * 8);
      int slot2 = slot + 256;
      int r1 = slot2 >> 2, c1 = slot2 & 3;
      gl_lds16(A + (size_t)(brow + r1) * K + kt + c1 * 8, As + slot2 * 8);
      gl_lds16(Bw + (size_t)(bcol + r1) * K + kt + c1 * 8, Bs + slot2 * 8);
    }
    asm volatile("s_waitcnt vmcnt(0)" ::: "memory");
    __syncthreads();

    bf16x8 af[4], bfr[4];
#pragma unroll
    for (int m = 0; m < 4; ++m)
      af[m] = *(const bf16x8*)(As + (wr * 64 + m * 16 + lrow) * 32 + lk * 8);
#pragma unroll
    for (int n = 0; n < 4; ++n)
      bfr[n] = *(const bf16x8*)(Bs + (wc * 64 + n * 16 + lrow) * 32 + lk * 8);
#pragma unroll
    for (int m = 0; m < 4; ++m) {
#pragma unroll
      for (int n = 0; n < 4; ++n)
        acc[m][n] = __builtin_amdgcn_mfma_f32_16x16x32_bf16(af[m], bfr[n], acc[m][n], 0, 0, 0);
    }
  }

#pragma unroll
  for (int m = 0; m < 4; ++m) {
    int rg0 = brow + wr * 64 + m * 16 + lk * 4;
#pragma unroll
    for (int n = 0; n < 4; ++n) {
      int cg = bcol + wc * 64 + n * 16 + lrow;
      float bv = bias[cg];
#pragma unroll
      for (int i = 0; i < 4; ++i) {
        int rg = rg0 + i;
        float val = (acc[m][n][i] + bv) * scale;
        int bb = rg >> 11, tt = rg & (T_DIM - 1);
        int hh = cg >> 6, dd = cg & 63;
        Out[(((size_t)bb * H_DIM + hh) * T_DIM + tt) * D_DIM + dd] = f2b(val);
      }
    }
  }
}

// ---------------- output projection GEMM: out = A @ W^T + b (f32 out) --------
__global__ __launch_bounds__(256) void k_gemm_proj(
    const u16* __restrict__ A, const u16* __restrict__ Bw,
    const float* __restrict__ bias, float* __restrict__ Cout) {
  __shared__ u16 As[128 * 32];
  __shared__ u16 Bs[128 * 32];
  const int tid = threadIdx.x;
  const int l = tid & 63;
  const int w = tid >> 6;
  const int wr = w >> 1, wc = w & 1;
  const int brow = blockIdx.y * 128, bcol = blockIdx.x * 128;
  const int lrow = l & 15, lk = l >> 4;
  const int K = C_DIM, N = C_DIM;

  f32x4 acc[4][4];
  for (int m = 0; m < 4; ++m)
    for (int n = 0; n < 4; ++n)
      acc[m][n] = (f32x4){0.f, 0.f, 0.f, 0.f};

  for (int kt = 0; kt < K; kt += 32) {
    __syncthreads();
    {
      int slot = tid;
      int r0 = slot >> 2, c0 = slot & 3;
      gl_lds16(A + (size_t)(brow + r0) * K + kt + c0 * 8, As + slot * 8);
      gl_lds16(Bw + (size_t)(bcol + r0) * K + kt + c0 * 8, Bs + slot * 8);
      int slot2 = slot + 256;
      int r1 = slot2 >> 2, c1 = slot2 & 3;
      gl_lds16(A + (size_t)(brow + r1) * K + kt + c1 * 8, As + slot2 * 8);
      gl_lds16(Bw + (size_t)(bcol + r1) * K + kt + c1 * 8, Bs + slot2 * 8);
    }
    asm volatile("s_waitcnt vmcnt(0)" ::: "memory");
    __syncthreads();

    bf16x8 af[4], bfr[4];
#pragma unroll
    for (int m = 0; m < 4; ++m)
      af[m] = *(const bf16x8*)(As + (wr * 64 + m * 16 + lrow) * 32 + lk * 8);
#pragma unroll
    for (int n = 0; n < 4; ++n)
      bfr[n] = *(const bf16x8*)(Bs + (wc * 64 + n * 16 + lrow) * 32 + lk * 8);
#pragma unroll
    for (int m = 0; m < 4; ++m) {
#pragma unroll
      for (int n = 0; n < 4; ++n)
        acc[m][n] = __builtin_amdgcn_mfma_f32_16x16x32_bf16(af[m], bfr[n], acc[m][n], 0, 0, 0);
    }
  }

#pragma unroll
  for (int m = 0; m < 4; ++m) {
    int rg0 = brow + wr * 64 + m * 16 + lk * 4;
#pragma unroll
    for (int n = 0; n < 4; ++n) {
      int cg = bcol + wc * 64 + n * 16 + lrow;
      float bv = bias[cg];
#pragma unroll
      for (int i = 0; i < 4; ++i)
        Cout[(size_t)(rg0 + i) * N + cg] = acc[m][n][i] + bv;
    }
  }
}

// ---------------- V transpose: [B,H,T,D] -> [B,H,D,T] ----------------
__global__ __launch_bounds__(256) void k_transpose(
    const u16* __restrict__ V, u16* __restrict__ Vt) {
  __shared__ u16 tile[64][65];
  const int tid = threadIdx.x;
  const int bh = blockIdx.y;
  const int t0 = blockIdx.x * 64;
  const size_t ibase = (size_t)bh * T_DIM * D_DIM + (size_t)t0 * D_DIM;
  const size_t obase = (size_t)bh * D_DIM * T_DIM + t0;

#pragma unroll
  for (int it = 0; it < 2; ++it) {
    int row = (tid >> 3) + it * 32;
    int blk = tid & 7;
    u16x8 v = *(const u16x8*)(V + ibase + (size_t)row * D_DIM + blk * 8);
#pragma unroll
    for (int j = 0; j < 8; ++j) tile[row][blk * 8 + j] = v[j];
  }
  __syncthreads();
#pragma unroll
  for (int it = 0; it < 2; ++it) {
    int d = (tid >> 3) + it * 32;
    int blk = tid & 7;
    u16x8 v;
#pragma unroll
    for (int j = 0; j < 8; ++j) v[j] = tile[blk * 8 + j][d];
    *(u16x8*)(Vt + obase + (size_t)d * T_DIM + blk * 8) = v;
  }
}

// ---------------- causal flash attention (double-buffered K/V) ----------------
// Q [B,H,T,D] (pre-scaled by QK_SCALE, exp2 domain), K [B,H,T,D], Vt [B,H,D,T];
// O [B,T,H*D] bf16. grid = (bh=64, 16); qb reversed so heavy blocks launch first.
__global__ __launch_bounds__(256) void k_attn(
    const u16* __restrict__ Q, const u16* __restrict__ Kg,
    const u16* __restrict__ Vt, u16* __restrict__ O) {
  __shared__ u16 Ks[2][64 * 64];
  __shared__ u16 Vs[2][64 * 64];
  __shared__ u16 Ps[4][32 * 72];

  const int tid = threadIdx.x;
  const int l = tid & 63;
  const int w = tid >> 6;
  const int bh = blockIdx.x;
  const int qb = 15 - blockIdx.y;          // heavy (high-qb) blocks dispatch first
  const int q0 = qb * 128;
  const int lrow = l & 15, lk = l >> 4;

  const size_t qkbase = (size_t)bh * T_DIM * D_DIM;
  const size_t vtbase = (size_t)bh * D_DIM * T_DIM;

  // staging coords (per-thread, fixed)
  const int sr0 = tid >> 3, sc0 = tid & 7;
  const int sr1 = (tid + 256) >> 3, sc1 = tid & 7;
  const int kcol0 = (sc0 ^ (sr0 & 7)) * 8;
  const int kcol1 = (sc1 ^ (sr1 & 7)) * 8;

#define STAGE(buf, kt)                                                                   \
  {                                                                                      \
    gl_lds16(Kg + qkbase + (size_t)((kt) * 64 + sr0) * D_DIM + kcol0, Ks[buf] + tid * 8);\
    gl_lds16(Vt + vtbase + (size_t)sr0 * T_DIM + (kt) * 64 + kcol0, Vs[buf] + tid * 8);  \
    gl_lds16(Kg + qkbase + (size_t)((kt) * 64 + sr1) * D_DIM + kcol1,                    \
             Ks[buf] + (tid + 256) * 8);                                                 \
    gl_lds16(Vt + vtbase + (size_t)sr1 * T_DIM + (kt) * 64 + kcol1,                      \
             Vs[buf] + (tid + 256) * 8);                                                 \
  }

  // Q fragments in registers for the whole block
  bf16x8 qf[2][2];
#pragma unroll
  for (int m = 0; m < 2; ++m) {
#pragma unroll
    for (int kk = 0; kk < 2; ++kk)
      qf[m][kk] = *(const bf16x8*)(Q + qkbase +
          (size_t)(q0 + w * 32 + m * 16 + lrow) * D_DIM + kk * 32 + lk * 8);
  }

  f32x4 o[2][4];
  float m_run[2][4], l_run[2][4];
#pragma unroll
  for (int m = 0; m < 2; ++m) {
#pragma unroll
    for (int n = 0; n < 4; ++n) o[m][n] = (f32x4){0.f, 0.f, 0.f, 0.f};
#pragma unroll
    for (int i = 0; i < 4; ++i) { m_run[m][i] = -1e30f; l_run[m][i] = 0.f; }
  }

  const int diag = q0 >> 6;
  const int nkt = diag + 2;
  const int wq_hi = q0 + w * 32 + 31;      // last q row owned by this wave

  STAGE(0, 0);

  for (int kt = 0; kt < nkt; ++kt) {
    const int cur = kt & 1;
    if (kt + 1 < nkt) {
      STAGE(cur ^ 1, kt + 1);
      asm volatile("s_waitcnt vmcnt(4)" ::: "memory");
    } else {
      asm volatile("s_waitcnt vmcnt(0)" ::: "memory");
    }
    __syncthreads();   // tile kt fully staged

    if (kt * 64 <= wq_hi) {   // skip fully-masked tiles (wave-uniform)
      // ---- S = Q @ K^T ----
      f32x4 s[2][4];
#pragma unroll
      for (int m = 0; m < 2; ++m)
#pragma unroll
        for (int n = 0; n < 4; ++n) s[m][n] = (f32x4){0.f, 0.f, 0.f, 0.f};

#pragma unroll
      for (int kk = 0; kk < 2; ++kk) {
        bf16x8 kf[4];
#pragma unroll
        for (int n = 0; n < 4; ++n) {
          int row = n * 16 + lrow;
          int blk = (kk * 4 + lk) ^ (row & 7);
          kf[n] = *(const bf16x8*)(Ks[cur] + row * 64 + blk * 8);
        }
#pragma unroll
        for (int m = 0; m < 2; ++m) {
#pragma unroll
          for (int n = 0; n < 4; ++n)
            s[m][n] = __builtin_amdgcn_mfma_f32_16x16x32_bf16(qf[m][kk], kf[n], s[m][n], 0, 0, 0);
        }
      }

      // ---- causal mask ----
      if (kt >= diag) {
#pragma unroll
        for (int m = 0; m < 2; ++m) {
#pragma unroll
          for (int i = 0; i < 4; ++i) {
            int qg = q0 + w * 32 + m * 16 + lk * 4 + i;
#pragma unroll
            for (int n = 0; n < 4; ++n) {
              int kg = kt * 64 + n * 16 + lrow;
              if (kg > qg) s[m][n][i] = -1e30f;
            }
          }
        }
      }

      // ---- online softmax (exp2 domain), defer-max THR=8 ----
#pragma unroll
      for (int m = 0; m < 2; ++m) {
        float pm[4], rs[4];
#pragma unroll
        for (int i = 0; i < 4; ++i)
          pm[i] = fmaxf(fmaxf(s[m][0][i], s[m][1][i]), fmaxf(s[m][2][i], s[m][3][i]));
#pragma unroll
        for (int off = 1; off < 16; off <<= 1) {
#pragma unroll
          for (int i = 0; i < 4; ++i)
            pm[i] = fmaxf(pm[i], __shfl_xor(pm[i], off, 64));
        }
        bool grow = false;
#pragma unroll
        for (int i = 0; i < 4; ++i) grow = grow || (pm[i] > m_run[m][i] + 8.f);
        if (__any(grow)) {
#pragma unroll
          for (int i = 0; i < 4; ++i) {
            float mn = fmaxf(m_run[m][i], pm[i]);
            float sc = exp2f(m_run[m][i] - mn);
            m_run[m][i] = mn;
            l_run[m][i] *= sc;
#pragma unroll
            for (int n = 0; n < 4; ++n) o[m][n][i] *= sc;
          }
        }
#pragma unroll
        for (int i = 0; i < 4; ++i) rs[i] = 0.f;
#pragma unroll
        for (int n = 0; n < 4; ++n) {
#pragma unroll
          for (int i = 0; i < 4; ++i) {
            float p = exp2f(s[m][n][i] - m_run[m][i]);
            s[m][n][i] = p;
            rs[i] += p;
          }
        }
#pragma unroll
        for (int off = 1; off < 16; off <<= 1) {
#pragma unroll
          for (int i = 0; i < 4; ++i)
            rs[i] += __shfl_xor(rs[i], off, 64);
        }
#pragma unroll
        for (int i = 0; i < 4; ++i) l_run[m][i] += rs[i];

        // P -> per-wave LDS
#pragma unroll
        for (int n = 0; n < 4; ++n) {
#pragma unroll
          for (int i = 0; i < 4; ++i) {
            int prow = m * 16 + lk * 4 + i;
            Ps[w][prow * 72 + n * 16 + lrow] = f2b(s[m][n][i]);
          }
        }
      }

      // ---- O += P @ V ----
#pragma unroll
      for (int kk = 0; kk < 2; ++kk) {
        bf16x8 pf[2], vf[4];
#pragma unroll
        for (int m = 0; m < 2; ++m)
          pf[m] = *(const bf16x8*)(&Ps[w][(m * 16 + lrow) * 72 + kk * 32 + lk * 8]);
#pragma unroll
        for (int n = 0; n < 4; ++n) {
          int row = n * 16 + lrow;
          int blk = (kk * 4 + lk) ^ (row & 7);
          vf[n] = *(const bf16x8*)(Vs[cur] + row * 64 + blk * 8);
        }
#pragma unroll
        for (int m = 0; m < 2; ++m) {
#pragma unroll
          for (int n = 0; n < 4; ++n)
            o[m][n] = __builtin_amdgcn_mfma_f32_16x16x32_bf16(pf[m], vf[n], o[m][n], 0, 0, 0);
        }
      }
    }
    __syncthreads();   // all waves done reading buffers before next STAGE overwrites
  }

  // ---- write O [B,T,H*D] bf16 ----
  const int bb = bh >> 4, hh = bh & 15;
#pragma unroll
  for (int m = 0; m < 2; ++m) {
#pragma unroll
    for (int i = 0; i < 4; ++i) {
      int t = q0 + w * 32 + m * 16 + lk * 4 + i;
      float inv = 1.f / l_run[m][i];
#pragma unroll
      for (int n = 0; n < 4; ++n) {
        O[((size_t)bb * T_DIM + t) * C_DIM + hh * D_DIM + n * 16 + lrow] =
            f2b(o[m][n][i] * inv);
      }
    }
  }
}

// ---------------- host launcher ----------------
extern "C" void kernel_launch(void* const* d_in, const int* in_sizes, int n_in,
                              void* d_out, int out_size, void* d_ws, size_t ws_size,
                              hipStream_t stream) {
  (void)in_sizes; (void)n_in; (void)out_size; (void)ws_size;
  const float* x  = (const float*)d_in[0];
  const float* wq = (const float*)d_in[1];
  const float* bq = (const float*)d_in[2];
  const float* wk = (const float*)d_in[3];
  const float* bk = (const float*)d_in[4];
  const float* wv = (const float*)d_in[5];
  const float* bv = (const float*)d_in[6];
  const float* wo = (const float*)d_in[7];
  const float* bo = (const float*)d_in[8];
  float* out = (float*)d_out;

  u16* xb  = (u16*)d_ws;
  u16* wqb = xb + (size_t)M_DIM * C_DIM;
  u16* wkb = wqb + (size_t)C_DIM * C_DIM;
  u16* wvb = wkb + (size_t)C_DIM * C_DIM;
  u16* wob = wvb + (size_t)C_DIM * C_DIM;
  u16* Qb  = wob + (size_t)C_DIM * C_DIM;
  u16* Kb  = Qb + (size_t)M_DIM * C_DIM;
  u16* Vb  = Kb + (size_t)M_DIM * C_DIM;
  u16* Vtb = Vb + (size_t)M_DIM * C_DIM;
  u16* Ob  = Vb;  // alias: V consumed by k_transpose before k_attn writes O

  int n4x = M_DIM * C_DIM / 4;
  k_cvt<<<(n4x + 255) / 256, 256, 0, stream>>>(x, xb, n4x);
  k_cvtw<<<4096, 256, 0, stream>>>(wq, wk, wv, wo, wqb, wkb, wvb, wob);

  k_gemm_qkv<<<dim3(24, M_DIM / 128), 256, 0, stream>>>(
      xb, wqb, wkb, wvb, bq, bk, bv, Qb, Kb, Vb);

  k_transpose<<<dim3(T_DIM / 64, B_DIM * H_DIM), 256, 0, stream>>>(Vb, Vtb);
  k_attn<<<dim3(B_DIM * H_DIM, 16), 256, 0, stream>>>(Qb, Kb, Vtb, Ob);
  k_gemm_proj<<<dim3(C_DIM / 128, M_DIM / 128), 256, 0, stream>>>(Ob, wob, bo, out);
}

// Round 3
// 202.679 us; speedup vs baseline: 1.8079x; 1.1967x over previous
//
#include <hip/hip_runtime.h>
#include <stdint.h>

#define B_DIM 4
#define T_DIM 2048
#define C_DIM 1024
#define H_DIM 16
#define D_DIM 64
#define M_DIM (B_DIM * T_DIM)   // 8192
// 1/sqrt(D) * log2(e): QK^T lands in exp2 domain
#define QK_SCALE 0.18033688011112042f

typedef float f32x4 __attribute__((ext_vector_type(4)));
typedef float f32x16 __attribute__((ext_vector_type(16)));
typedef short bf16x8 __attribute__((ext_vector_type(8)));
typedef unsigned short u16;
typedef u16 u16x8 __attribute__((ext_vector_type(8)));

// single-instruction RNE f32->bf16 (low 16 bits of dest)
static __device__ __forceinline__ u16 f2b(float f) {
  uint32_t r;
  asm("v_cvt_pk_bf16_f32 %0, %1, %1" : "=v"(r) : "v"(f));
  return (u16)r;
}
// pack 2 f32 -> u32 of 2 bf16 (lo=a, hi=b)
static __device__ __forceinline__ uint32_t f2b2(float a, float b) {
  uint32_t r;
  asm("v_cvt_pk_bf16_f32 %0, %1, %2" : "=v"(r) : "v"(a), "v"(b));
  return r;
}

static __device__ __forceinline__ void gl_lds16(const u16* g, u16* l) {
  __builtin_amdgcn_global_load_lds(
      (const __attribute__((address_space(1))) void*)g,
      (__attribute__((address_space(3))) void*)l, 16, 0, 0);
}

// ---------------- f32 -> bf16 converts ----------------
__global__ void k_cvt(const float* __restrict__ src, u16* __restrict__ dst, int n4) {
  int i = blockIdx.x * blockDim.x + threadIdx.x;
  if (i < n4) {
    float4 v = ((const float4*)src)[i];
    uint2 o;
    o.x = f2b2(v.x, v.y);
    o.y = f2b2(v.z, v.w);
    ((uint2*)dst)[i] = o;
  }
}

// all four weight matrices in one dispatch; each is C*C floats = 2^18 float4
__global__ void k_cvtw(const float* __restrict__ s0, const float* __restrict__ s1,
                       const float* __restrict__ s2, const float* __restrict__ s3,
                       u16* __restrict__ d0, u16* __restrict__ d1,
                       u16* __restrict__ d2, u16* __restrict__ d3) {
  int i = blockIdx.x * blockDim.x + threadIdx.x;
  int seg = i >> 18;
  int j = i & ((1 << 18) - 1);
  const float* s = seg == 0 ? s0 : seg == 1 ? s1 : seg == 2 ? s2 : s3;
  u16* d = seg == 0 ? d0 : seg == 1 ? d1 : seg == 2 ? d2 : d3;
  float4 v = ((const float4*)s)[j];
  uint2 o;
  o.x = f2b2(v.x, v.y);
  o.y = f2b2(v.z, v.w);
  ((uint2*)d)[j] = o;
}

// ---------------- fused QKV GEMM ----------------
__global__ __launch_bounds__(256) void k_gemm_qkv(
    const u16* __restrict__ A,
    const u16* __restrict__ w0, const u16* __restrict__ w1, const u16* __restrict__ w2,
    const float* __restrict__ b0, const float* __restrict__ b1, const float* __restrict__ b2,
    u16* __restrict__ Qo, u16* __restrict__ Ko, u16* __restrict__ Vo) {
  __shared__ u16 As[128 * 32];
  __shared__ u16 Bs[128 * 32];
  const int tid = threadIdx.x;
  const int l = tid & 63;
  const int w = tid >> 6;
  const int wr = w >> 1, wc = w & 1;
  const int seg = blockIdx.x >> 3;
  const int brow = blockIdx.y * 128, bcol = (blockIdx.x & 7) * 128;
  const int lrow = l & 15, lk = l >> 4;
  const int K = C_DIM;

  const u16* Bw = seg == 0 ? w0 : seg == 1 ? w1 : w2;
  const float* bias = seg == 0 ? b0 : seg == 1 ? b1 : b2;
  u16* Out = seg == 0 ? Qo : seg == 1 ? Ko : Vo;
  const float scale = seg == 0 ? QK_SCALE : 1.f;

  f32x4 acc[4][4];
  for (int m = 0; m < 4; ++m)
    for (int n = 0; n < 4; ++n)
      acc[m][n] = (f32x4){0.f, 0.f, 0.f, 0.f};

  for (int kt = 0; kt < K; kt += 32) {
    __syncthreads();
    {
      int slot = tid;
      int r0 = slot >> 2, c0 = slot & 3;
      gl_lds16(A + (size_t)(brow + r0) * K + kt + c0 * 8, As + slot * 8);
      gl_lds16(Bw + (size_t)(bcol + r0) * K + kt + c0 * 8, Bs + slot * 8);
      int slot2 = slot + 256;
      int r1 = slot2 >> 2, c1 = slot2 & 3;
      gl_lds16(A + (size_t)(brow + r1) * K + kt + c1 * 8, As + slot2 * 8);
      gl_lds16(Bw + (size_t)(bcol + r1) * K + kt + c1 * 8, Bs + slot2 * 8);
    }
    asm volatile("s_waitcnt vmcnt(0)" ::: "memory");
    __syncthreads();

    bf16x8 af[4], bfr[4];
#pragma unroll
    for (int m = 0; m < 4; ++m)
      af[m] = *(const bf16x8*)(As + (wr * 64 + m * 16 + lrow) * 32 + lk * 8);
#pragma unroll
    for (int n = 0; n < 4; ++n)
      bfr[n] = *(const bf16x8*)(Bs + (wc * 64 + n * 16 + lrow) * 32 + lk * 8);
#pragma unroll
    for (int m = 0; m < 4; ++m) {
#pragma unroll
      for (int n = 0; n < 4; ++n)
        acc[m][n] = __builtin_amdgcn_mfma_f32_16x16x32_bf16(af[m], bfr[n], acc[m][n], 0, 0, 0);
    }
  }

#pragma unroll
  for (int m = 0; m < 4; ++m) {
    int rg0 = brow + wr * 64 + m * 16 + lk * 4;
#pragma unroll
    for (int n = 0; n < 4; ++n) {
      int cg = bcol + wc * 64 + n * 16 + lrow;
      float bv = bias[cg];
#pragma unroll
      for (int i = 0; i < 4; ++i) {
        int rg = rg0 + i;
        float val = (acc[m][n][i] + bv) * scale;
        int bb = rg >> 11, tt = rg & (T_DIM - 1);
        int hh = cg >> 6, dd = cg & 63;
        Out[(((size_t)bb * H_DIM + hh) * T_DIM + tt) * D_DIM + dd] = f2b(val);
      }
    }
  }
}

// ---------------- output projection GEMM: out = A @ W^T + b (f32 out) --------
__global__ __launch_bounds__(256) void k_gemm_proj(
    const u16* __restrict__ A, const u16* __restrict__ Bw,
    const float* __restrict__ bias, float* __restrict__ Cout) {
  __shared__ u16 As[128 * 32];
  __shared__ u16 Bs[128 * 32];
  const int tid = threadIdx.x;
  const int l = tid & 63;
  const int w = tid >> 6;
  const int wr = w >> 1, wc = w & 1;
  const int brow = blockIdx.y * 128, bcol = blockIdx.x * 128;
  const int lrow = l & 15, lk = l >> 4;
  const int K = C_DIM, N = C_DIM;

  f32x4 acc[4][4];
  for (int m = 0; m < 4; ++m)
    for (int n = 0; n < 4; ++n)
      acc[m][n] = (f32x4){0.f, 0.f, 0.f, 0.f};

  for (int kt = 0; kt < K; kt += 32) {
    __syncthreads();
    {
      int slot = tid;
      int r0 = slot >> 2, c0 = slot & 3;
      gl_lds16(A + (size_t)(brow + r0) * K + kt + c0 * 8, As + slot * 8);
      gl_lds16(Bw + (size_t)(bcol + r0) * K + kt + c0 * 8, Bs + slot * 8);
      int slot2 = slot + 256;
      int r1 = slot2 >> 2, c1 = slot2 & 3;
      gl_lds16(A + (size_t)(brow + r1) * K + kt + c1 * 8, As + slot2 * 8);
      gl_lds16(Bw + (size_t)(bcol + r1) * K + kt + c1 * 8, Bs + slot2 * 8);
    }
    asm volatile("s_waitcnt vmcnt(0)" ::: "memory");
    __syncthreads();

    bf16x8 af[4], bfr[4];
#pragma unroll
    for (int m = 0; m < 4; ++m)
      af[m] = *(const bf16x8*)(As + (wr * 64 + m * 16 + lrow) * 32 + lk * 8);
#pragma unroll
    for (int n = 0; n < 4; ++n)
      bfr[n] = *(const bf16x8*)(Bs + (wc * 64 + n * 16 + lrow) * 32 + lk * 8);
#pragma unroll
    for (int m = 0; m < 4; ++m) {
#pragma unroll
      for (int n = 0; n < 4; ++n)
        acc[m][n] = __builtin_amdgcn_mfma_f32_16x16x32_bf16(af[m], bfr[n], acc[m][n], 0, 0, 0);
    }
  }

#pragma unroll
  for (int m = 0; m < 4; ++m) {
    int rg0 = brow + wr * 64 + m * 16 + lk * 4;
#pragma unroll
    for (int n = 0; n < 4; ++n) {
      int cg = bcol + wc * 64 + n * 16 + lrow;
      float bv = bias[cg];
#pragma unroll
      for (int i = 0; i < 4; ++i)
        Cout[(size_t)(rg0 + i) * N + cg] = acc[m][n][i] + bv;
    }
  }
}

// ---------------- V transpose: [B,H,T,D] -> [B,H,D,T] ----------------
__global__ __launch_bounds__(256) void k_transpose(
    const u16* __restrict__ V, u16* __restrict__ Vt) {
  __shared__ u16 tile[64][65];
  const int tid = threadIdx.x;
  const int bh = blockIdx.y;
  const int t0 = blockIdx.x * 64;
  const size_t ibase = (size_t)bh * T_DIM * D_DIM + (size_t)t0 * D_DIM;
  const size_t obase = (size_t)bh * D_DIM * T_DIM + t0;

#pragma unroll
  for (int it = 0; it < 2; ++it) {
    int row = (tid >> 3) + it * 32;
    int blk = tid & 7;
    u16x8 v = *(const u16x8*)(V + ibase + (size_t)row * D_DIM + blk * 8);
#pragma unroll
    for (int j = 0; j < 8; ++j) tile[row][blk * 8 + j] = v[j];
  }
  __syncthreads();
#pragma unroll
  for (int it = 0; it < 2; ++it) {
    int d = (tid >> 3) + it * 32;
    int blk = tid & 7;
    u16x8 v;
#pragma unroll
    for (int j = 0; j < 8; ++j) v[j] = tile[blk * 8 + j][d];
    *(u16x8*)(Vt + obase + (size_t)d * T_DIM + blk * 8) = v;
  }
}

// ---------------- causal flash attention, swapped-operand in-register softmax ----
// Q [B,H,T,D] (pre-scaled, exp2 domain), K [B,H,T,D], Vt [B,H,D,T]; O [B,T,C] bf16.
// 4 waves x 32 q-rows; KVBLK=64; S^T = mfma(K, Q^T) so each lane owns one q-row.
__global__ __launch_bounds__(256) void k_attn(
    const u16* __restrict__ Q, const u16* __restrict__ Kg,
    const u16* __restrict__ Vt, u16* __restrict__ O) {
  __shared__ u16 Ks[2][64 * 64];
  __shared__ u16 Vs[2][64 * 64];

  const int tid = threadIdx.x;
  const int l = tid & 63;
  const int w = tid >> 6;
  const int bh = blockIdx.x;
  const int qb = 15 - blockIdx.y;          // heavy blocks dispatch first
  const int q0 = qb * 128;
  const int ql = l & 31;                   // lane's q row (MFMA col)
  const int hi = l >> 5;
  const int r0 = q0 + w * 32;              // wave's first q row
  const int qg = r0 + ql;                  // lane's global q row

  const size_t qkbase = (size_t)bh * T_DIM * D_DIM;
  const size_t vtbase = (size_t)bh * D_DIM * T_DIM;

  // staging coords (per-thread, fixed); XOR pre-swizzle on the global source
  const int sr0 = tid >> 3, sc = tid & 7;
  const int sr1 = (tid + 256) >> 3;
  const int kcol0 = (sc ^ (sr0 & 7)) * 8;
  const int kcol1 = (sc ^ (sr1 & 7)) * 8;

#define STAGE(buf, kt)                                                                   \
  {                                                                                      \
    gl_lds16(Kg + qkbase + (size_t)((kt) * 64 + sr0) * D_DIM + kcol0, Ks[buf] + tid * 8);\
    gl_lds16(Vt + vtbase + (size_t)sr0 * T_DIM + (kt) * 64 + kcol0, Vs[buf] + tid * 8);  \
    gl_lds16(Kg + qkbase + (size_t)((kt) * 64 + sr1) * D_DIM + kcol1,                    \
             Ks[buf] + (tid + 256) * 8);                                                 \
    gl_lds16(Vt + vtbase + (size_t)sr1 * T_DIM + (kt) * 64 + kcol1,                      \
             Vs[buf] + (tid + 256) * 8);                                                 \
  }

  // Q fragments (B-operand): lane -> Q[q=ql][d = kk*16 + hi*8 + j]
  bf16x8 qf[4];
#pragma unroll
  for (int kk = 0; kk < 4; ++kk)
    qf[kk] = *(const bf16x8*)(Q + qkbase + (size_t)qg * D_DIM + kk * 16 + hi * 8);

  f32x16 oacc[2];
#pragma unroll
  for (int dt = 0; dt < 2; ++dt)
#pragma unroll
    for (int r = 0; r < 16; ++r) oacc[dt][r] = 0.f;
  float m_run = -1e30f, l_run = 0.f;

  const int tdiag = r0 >> 6;               // wave's diagonal tile
  const int nkt = (q0 >> 6) + 2;           // block tile count

  STAGE(0, 0);

  for (int kt = 0; kt < nkt; ++kt) {
    const int cur = kt & 1;
    if (kt + 1 < nkt) {
      STAGE(cur ^ 1, kt + 1);
      asm volatile("s_waitcnt vmcnt(4)" ::: "memory");
    } else {
      asm volatile("s_waitcnt vmcnt(0)" ::: "memory");
    }
    __syncthreads();

    if (kt <= tdiag) {
      // ---- S^T = K_tile @ Q^T : lane holds S[q=ql][kv = a*32 + crow(r,hi)] ----
      f32x16 s[2];
#pragma unroll
      for (int a = 0; a < 2; ++a)
#pragma unroll
        for (int r = 0; r < 16; ++r) s[a][r] = 0.f;

#pragma unroll
      for (int kk = 0; kk < 4; ++kk) {
#pragma unroll
        for (int a = 0; a < 2; ++a) {
          int row = a * 32 + ql;
          int blk = (kk * 2 + hi) ^ (row & 7);
          bf16x8 kf = *(const bf16x8*)(Ks[cur] + row * 64 + blk * 8);
          s[a] = __builtin_amdgcn_mfma_f32_32x32x16_bf16(kf, qf[kk], s[a], 0, 0, 0);
        }
      }

      // ---- causal mask (wave's diagonal tile only) ----
      if (kt == tdiag) {
#pragma unroll
        for (int a = 0; a < 2; ++a) {
#pragma unroll
          for (int r = 0; r < 16; ++r) {
            int kv = kt * 64 + a * 32 + (r & 3) + 8 * (r >> 2) + 4 * hi;
            if (kv > qg) s[a][r] = -1e30f;
          }
        }
      }

      // ---- row max: in-register tree + one cross-half shfl ----
      float t[16];
#pragma unroll
      for (int r = 0; r < 16; ++r) t[r] = fmaxf(s[0][r], s[1][r]);
#pragma unroll
      for (int r = 0; r < 8; ++r) t[r] = fmaxf(t[r], t[r + 8]);
#pragma unroll
      for (int r = 0; r < 4; ++r) t[r] = fmaxf(t[r], t[r + 4]);
      float pm = fmaxf(fmaxf(t[0], t[1]), fmaxf(t[2], t[3]));
      pm = fmaxf(pm, __shfl_xor(pm, 32, 64));

      // ---- defer-max (THR=8 in exp2 domain) ----
      if (__any(pm > m_run + 8.f)) {
        float mn = fmaxf(m_run, pm);
        float sc = exp2f(m_run - mn);
        m_run = mn;
        l_run *= sc;
#pragma unroll
        for (int dt = 0; dt < 2; ++dt)
#pragma unroll
          for (int r = 0; r < 16; ++r) oacc[dt][r] *= sc;
      }

      // ---- P = exp2(S - m), row sum ----
      float rs0 = 0.f, rs1 = 0.f, rs2 = 0.f, rs3 = 0.f;
#pragma unroll
      for (int a = 0; a < 2; ++a) {
#pragma unroll
        for (int r = 0; r < 16; ++r) {
          float p = exp2f(s[a][r] - m_run);
          s[a][r] = p;
          if ((r & 3) == 0) rs0 += p;
          else if ((r & 3) == 1) rs1 += p;
          else if ((r & 3) == 2) rs2 += p;
          else rs3 += p;
        }
      }
      float rs = (rs0 + rs1) + (rs2 + rs3);
      rs += __shfl_xor(rs, 32, 64);
      l_run += rs;

      // ---- PV: O^T += V^T @ P^T, P-frags built in-register ----
#pragma unroll
      for (int kk = 0; kk < 4; ++kk) {
        const int a = kk >> 1;
        const int base = (kk & 1) * 8;
        union { uint32_t wd[4]; bf16x8 v; } pf;
#pragma unroll
        for (int i = 0; i < 2; ++i) {
          uint32_t Aw = f2b2(s[a][base + 2 * i], s[a][base + 2 * i + 1]);
          uint32_t Bw = f2b2(s[a][base + 4 + 2 * i], s[a][base + 5 + 2 * i]);
          uint32_t As_ = (uint32_t)__shfl_xor((int)Aw, 32, 64);
          uint32_t Bs_ = (uint32_t)__shfl_xor((int)Bw, 32, 64);
          pf.wd[i] = hi ? Bs_ : Aw;
          pf.wd[2 + i] = hi ? Bw : As_;
        }
#pragma unroll
        for (int dt = 0; dt < 2; ++dt) {
          int row = dt * 32 + ql;
          int blk = (kk * 2 + hi) ^ (row & 7);
          bf16x8 vf = *(const bf16x8*)(Vs[cur] + row * 64 + blk * 8);
          oacc[dt] = __builtin_amdgcn_mfma_f32_32x32x16_bf16(vf, pf.v, oacc[dt], 0, 0, 0);
        }
      }
    }
    __syncthreads();   // buffers free before next STAGE overwrites
  }

  // ---- write O [B,T,C] bf16: lane owns row qg, d = crow(r,hi)+32*dt ----
  const int bb = bh >> 4, hh = bh & 15;
  const float inv = 1.f / l_run;
  u16* orow = O + ((size_t)bb * T_DIM + qg) * C_DIM + hh * D_DIM;
#pragma unroll
  for (int dt = 0; dt < 2; ++dt) {
#pragma unroll
    for (int g = 0; g < 4; ++g) {
      uint2 val;
      val.x = f2b2(oacc[dt][g * 4 + 0] * inv, oacc[dt][g * 4 + 1] * inv);
      val.y = f2b2(oacc[dt][g * 4 + 2] * inv, oacc[dt][g * 4 + 3] * inv);
      *(uint2*)(orow + dt * 32 + g * 8 + 4 * hi) = val;
    }
  }
}

// ---------------- host launcher ----------------
extern "C" void kernel_launch(void* const* d_in, const int* in_sizes, int n_in,
                              void* d_out, int out_size, void* d_ws, size_t ws_size,
                              hipStream_t stream) {
  (void)in_sizes; (void)n_in; (void)out_size; (void)ws_size;
  const float* x  = (const float*)d_in[0];
  const float* wq = (const float*)d_in[1];
  const float* bq = (const float*)d_in[2];
  const float* wk = (const float*)d_in[3];
  const float* bk = (const float*)d_in[4];
  const float* wv = (const float*)d_in[5];
  const float* bv = (const float*)d_in[6];
  const float* wo = (const float*)d_in[7];
  const float* bo = (const float*)d_in[8];
  float* out = (float*)d_out;

  u16* xb  = (u16*)d_ws;
  u16* wqb = xb + (size_t)M_DIM * C_DIM;
  u16* wkb = wqb + (size_t)C_DIM * C_DIM;
  u16* wvb = wkb + (size_t)C_DIM * C_DIM;
  u16* wob = wvb + (size_t)C_DIM * C_DIM;
  u16* Qb  = wob + (size_t)C_DIM * C_DIM;
  u16* Kb  = Qb + (size_t)M_DIM * C_DIM;
  u16* Vb  = Kb + (size_t)M_DIM * C_DIM;
  u16* Vtb = Vb + (size_t)M_DIM * C_DIM;
  u16* Ob  = Vb;  // alias: V consumed by k_transpose before k_attn writes O

  int n4x = M_DIM * C_DIM / 4;
  k_cvt<<<(n4x + 255) / 256, 256, 0, stream>>>(x, xb, n4x);
  k_cvtw<<<4096, 256, 0, stream>>>(wq, wk, wv, wo, wqb, wkb, wvb, wob);

  k_gemm_qkv<<<dim3(24, M_DIM / 128), 256, 0, stream>>>(
      xb, wqb, wkb, wvb, bq, bk, bv, Qb, Kb, Vb);

  k_transpose<<<dim3(T_DIM / 64, B_DIM * H_DIM), 256, 0, stream>>>(Vb, Vtb);
  k_attn<<<dim3(B_DIM * H_DIM, 16), 256, 0, stream>>>(Qb, Kb, Vtb, Ob);
  k_gemm_proj<<<dim3(C_DIM / 128, M_DIM / 128), 256, 0, stream>>>(Ob, wob, bo, out);
}